// Round 13
// baseline (177.107 us; speedup 1.0000x reference)
//
#include <hip/hip_runtime.h>
#include <hip/hip_bf16.h>

#define NN 100000
#define NE 3200000
#define NPB 64        // dst nodes per bucket
#define NB 1564       // 1564*64 = 100096 >= NN
#define CAP 2560      // mean 2046, sigma ~45 -> +11 sigma headroom
#define BATCH 4096    // edges staged per bin_k block (4096 -> 58KB LDS -> 2 blk/CU)
#define NGB 1563      // gemm blocks: 1563*64 = 100032 >= NN

typedef __hip_bfloat16 bf16;
typedef __attribute__((ext_vector_type(8))) short bf16x8;  // 8 bf16 (4 VGPR)
typedef __attribute__((ext_vector_type(4))) float f32x4;

__device__ __forceinline__ void fma4(float4& a, float s, const float4 w) {
  a.x = fmaf(s, w.x, a.x);
  a.y = fmaf(s, w.y, a.y);
  a.z = fmaf(s, w.z, a.z);
  a.w = fmaf(s, w.w, a.w);
}

__device__ __forceinline__ unsigned short f2b(float f) {  // f32 -> bf16 RNE
  unsigned u = __float_as_uint(f);
  unsigned r = ((u >> 16) & 1u) + 0x7FFFu;
  return (unsigned short)((u + r) >> 16);
}

__device__ __forceinline__ unsigned pack2(float lo, float hi) {
  return (unsigned)f2b(lo) | ((unsigned)f2b(hi) << 16);
}

// Binning v4: BATCH 4096 -> LDS ~58KB -> 2 blocks/CU (32 waves, was 16).
// Inline detect; LDS histogram -> bulk global range reservation -> LDS
// bucket-sort -> coalesced ordered write-out.
__global__ __launch_bounds__(1024) void bin_k(const void* __restrict__ eidx,
                                              int* __restrict__ bcur,
                                              int* __restrict__ buckets) {
  __shared__ int scnt[NB];
  __shared__ int sofs[NB];      // LDS run start
  __shared__ int sbase[NB];     // global run start (this block's reservation)
  __shared__ int lcur[NB];      // LDS scatter cursor
  __shared__ int tot;
  __shared__ int sflag;
  __shared__ int sorted[BATCH]; // 16 KB
  __shared__ int gaddr[BATCH];  // 16 KB
  int t = threadIdx.x;
  long long e0 = (long long)blockIdx.x * BATCH;
  int m = (int)((NE - e0 < BATCH) ? (NE - e0) : BATCH);

  // inline detect: int64 iff high dwords of first 64 values are all zero
  if (t < 64) {
    unsigned long long bb = __ballot(((const int*)eidx)[2 * t + 1] == 0);
    if (t == 0) sflag = (bb == 0xFFFFFFFFFFFFFFFFULL) ? 1 : 0;
  }
  for (int i = t; i < NB; i += 1024) scnt[i] = 0;
  if (t == 0) tot = 0;
  __syncthreads();
  int isI64 = sflag;

  int ent[BATCH / 1024], bv[BATCH / 1024];
#pragma unroll
  for (int j = 0; j < BATCH / 1024; j++) {
    int idx = t + j * 1024;
    bv[j] = -1;
    if (idx < m) {
      long long i = e0 + idx;
      int s, d;
      if (isI64) {
        s = (int)((const long long*)eidx)[i];
        d = (int)((const long long*)eidx)[NE + i];
      } else {
        s = ((const int*)eidx)[i];
        d = ((const int*)eidx)[NE + i];
      }
      bv[j] = d >> 6;
      ent[j] = s | ((d & 63) << 17);
      atomicAdd(&scnt[bv[j]], 1);
    }
  }
  __syncthreads();
  for (int i = t; i < NB; i += 1024) {
    int c = scnt[i];
    if (c) {
      sofs[i] = atomicAdd(&tot, c);
      sbase[i] = atomicAdd(&bcur[i], c);
      lcur[i] = sofs[i];
    }
  }
  __syncthreads();
#pragma unroll
  for (int j = 0; j < BATCH / 1024; j++) {
    if (bv[j] >= 0) {
      int pos = atomicAdd(&lcur[bv[j]], 1);
      sorted[pos] = ent[j];
      int gp = sbase[bv[j]] + (pos - sofs[bv[j]]);
      gaddr[pos] = (gp < CAP) ? bv[j] * CAP + gp : -1;
    }
  }
  __syncthreads();
  for (int i = t; i < m; i += 1024) {
    int ga = gaddr[i];
    if (ga >= 0) buckets[ga] = sorted[i];
  }
}

// cnt-lite + prep fused: blocks 0..NB-1 do the per-bucket histogram -> dinv
// (4-wave sub-histograms, no same-address contention); block NB converts W
// into MFMA-fragment-ordered bf16 hi/lo.
__global__ __launch_bounds__(256) void cnt_k(const int* __restrict__ buckets,
                                             const int* __restrict__ bcur,
                                             float* __restrict__ dinv,
                                             const float* __restrict__ W,
                                             unsigned short* __restrict__ wh,
                                             unsigned short* __restrict__ wl) {
  int b = blockIdx.x, t = threadIdx.x;
  if (b == NB) {   // ---- prep: W -> wh/wl fragment-ordered bf16 hi/lo
#pragma unroll 4
    for (int i = 0; i < 64; i++) {
      int idx = i * 256 + t;
      int j = idx & 7;
      int lane = (idx >> 3) & 63;
      int pair = idx >> 9;           // kk*4 + nf
      int nf = pair & 3, kk = pair >> 2;
      int k = kk * 32 + (lane >> 4) * 8 + j;
      int n = nf * 16 + (lane & 15);
      float w = W[k * 64 + n];
      unsigned short hh = f2b(w);
      float fh = __uint_as_float((unsigned)hh << 16);
      wh[idx] = hh;
      wl[idx] = f2b(w - fh);
    }
    return;
  }
  __shared__ int c4[4][NPB];
  int w = t >> 6;
  if (t < 128) { c4[0][t & 63] = 0; c4[1][t & 63] = 0; }
  else         { c4[2][t & 63] = 0; c4[3][t & 63] = 0; }
  __syncthreads();
  int m = bcur[b]; if (m > CAP) m = CAP;
  const int* bp = buckets + (size_t)b * CAP;
  for (int i = t; i < m; i += 256) atomicAdd(&c4[w][(bp[i] >> 17) & 63], 1);
  __syncthreads();
  int node = b * NPB + t;
  if (t < NPB && node < NN) {
    int s = c4[0][t] + c4[1][t] + c4[2][t] + c4[3][t];
    dinv[node] = rsqrtf((float)s + 1.0f);
  }
}

// h' = (x @ W_gcn) * dinv[row], bf16 out (dinv baked in).
// v13 (MFMA, full-row x preload): per lane the entire 64-float x window is
// issued as 16 upfront global_load_dwordx4; W frags register double-buffered
// one step ahead; sched_barrier(0) fences between steps cap the live set.
// acc += xh*Wh + xh*Wl + xl*Wh (f32 acc; error ~2^-17, numerically == f32).
// C/D layout (m89-verified): col=lane&15, row=(l>>4)*4+reg.
__global__ __launch_bounds__(256) void gemm_k(const float* __restrict__ x,
                                              const unsigned short* __restrict__ wh,
                                              const unsigned short* __restrict__ wl,
                                              const float* __restrict__ dinv,
                                              bf16* __restrict__ h) {
  int t = threadIdx.x;
  int wv = t >> 6, l = t & 63;
  int rowbase = blockIdx.x * 64 + wv * 16;
  int arow = rowbase + (l & 15);
  if (arow >= NN) arow = NN - 1;           // clamp loads, mask stores
  const float* xrow = x + (size_t)arow * 256 + (l >> 4) * 8;

  const bf16x8* whf = (const bf16x8*)wh;   // [ (kk*4+nf)*64 + lane ]
  const bf16x8* wlf = (const bf16x8*)wl;

  f32x4 acc0 = {0.f, 0.f, 0.f, 0.f};
  f32x4 acc1 = acc0, acc2 = acc0, acc3 = acc0;

  // -------- preload the lane's whole x window (16 dwordx4, all in flight)
  float4 x0a = *(const float4*)(xrow +   0), x0b = *(const float4*)(xrow +   4);
  float4 x1a = *(const float4*)(xrow +  32), x1b = *(const float4*)(xrow +  36);
  float4 x2a = *(const float4*)(xrow +  64), x2b = *(const float4*)(xrow +  68);
  float4 x3a = *(const float4*)(xrow +  96), x3b = *(const float4*)(xrow + 100);
  float4 x4a = *(const float4*)(xrow + 128), x4b = *(const float4*)(xrow + 132);
  float4 x5a = *(const float4*)(xrow + 160), x5b = *(const float4*)(xrow + 164);
  float4 x6a = *(const float4*)(xrow + 192), x6b = *(const float4*)(xrow + 196);
  float4 x7a = *(const float4*)(xrow + 224), x7b = *(const float4*)(xrow + 228);

  bf16x8 ha0, ha1, ha2, ha3, la0, la1, la2, la3;   // W set A
  bf16x8 hb0, hb1, hb2, hb3, lb0, lb1, lb2, lb3;   // W set B

#define LOADW(H0, H1, H2, H3, L0, L1, L2, L3, kk)                      \
  {                                                                    \
    int fb_ = (kk) * 256 + l;                                          \
    H0 = whf[fb_]; H1 = whf[fb_ + 64]; H2 = whf[fb_ + 128]; H3 = whf[fb_ + 192]; \
    L0 = wlf[fb_]; L1 = wlf[fb_ + 64]; L2 = wlf[fb_ + 128]; L3 = wlf[fb_ + 192]; \
  }
#define COMPUTE(Xa, Xb, H0, H1, H2, H3, L0, L1, L2, L3)                \
  {                                                                    \
    bf16x8 ah, al;                                                     \
    {                                                                  \
      unsigned short hh_; float fh_;                                   \
      hh_ = f2b(Xa.x); fh_ = __uint_as_float((unsigned)hh_ << 16); ah[0] = (short)hh_; al[0] = (short)f2b(Xa.x - fh_); \
      hh_ = f2b(Xa.y); fh_ = __uint_as_float((unsigned)hh_ << 16); ah[1] = (short)hh_; al[1] = (short)f2b(Xa.y - fh_); \
      hh_ = f2b(Xa.z); fh_ = __uint_as_float((unsigned)hh_ << 16); ah[2] = (short)hh_; al[2] = (short)f2b(Xa.z - fh_); \
      hh_ = f2b(Xa.w); fh_ = __uint_as_float((unsigned)hh_ << 16); ah[3] = (short)hh_; al[3] = (short)f2b(Xa.w - fh_); \
      hh_ = f2b(Xb.x); fh_ = __uint_as_float((unsigned)hh_ << 16); ah[4] = (short)hh_; al[4] = (short)f2b(Xb.x - fh_); \
      hh_ = f2b(Xb.y); fh_ = __uint_as_float((unsigned)hh_ << 16); ah[5] = (short)hh_; al[5] = (short)f2b(Xb.y - fh_); \
      hh_ = f2b(Xb.z); fh_ = __uint_as_float((unsigned)hh_ << 16); ah[6] = (short)hh_; al[6] = (short)f2b(Xb.z - fh_); \
      hh_ = f2b(Xb.w); fh_ = __uint_as_float((unsigned)hh_ << 16); ah[7] = (short)hh_; al[7] = (short)f2b(Xb.w - fh_); \
    }                                                                  \
    acc0 = __builtin_amdgcn_mfma_f32_16x16x32_bf16(ah, H0, acc0, 0, 0, 0); \
    acc1 = __builtin_amdgcn_mfma_f32_16x16x32_bf16(ah, H1, acc1, 0, 0, 0); \
    acc2 = __builtin_amdgcn_mfma_f32_16x16x32_bf16(ah, H2, acc2, 0, 0, 0); \
    acc3 = __builtin_amdgcn_mfma_f32_16x16x32_bf16(ah, H3, acc3, 0, 0, 0); \
    acc0 = __builtin_amdgcn_mfma_f32_16x16x32_bf16(ah, L0, acc0, 0, 0, 0); \
    acc1 = __builtin_amdgcn_mfma_f32_16x16x32_bf16(ah, L1, acc1, 0, 0, 0); \
    acc2 = __builtin_amdgcn_mfma_f32_16x16x32_bf16(ah, L2, acc2, 0, 0, 0); \
    acc3 = __builtin_amdgcn_mfma_f32_16x16x32_bf16(ah, L3, acc3, 0, 0, 0); \
    acc0 = __builtin_amdgcn_mfma_f32_16x16x32_bf16(al, H0, acc0, 0, 0, 0); \
    acc1 = __builtin_amdgcn_mfma_f32_16x16x32_bf16(al, H1, acc1, 0, 0, 0); \
    acc2 = __builtin_amdgcn_mfma_f32_16x16x32_bf16(al, H2, acc2, 0, 0, 0); \
    acc3 = __builtin_amdgcn_mfma_f32_16x16x32_bf16(al, H3, acc3, 0, 0, 0); \
  }
#define SBAR __builtin_amdgcn_sched_barrier(0);

  LOADW(ha0, ha1, ha2, ha3, la0, la1, la2, la3, 0)
  LOADW(hb0, hb1, hb2, hb3, lb0, lb1, lb2, lb3, 1)
  COMPUTE(x0a, x0b, ha0, ha1, ha2, ha3, la0, la1, la2, la3) SBAR
  LOADW(ha0, ha1, ha2, ha3, la0, la1, la2, la3, 2)
  COMPUTE(x1a, x1b, hb0, hb1, hb2, hb3, lb0, lb1, lb2, lb3) SBAR
  LOADW(hb0, hb1, hb2, hb3, lb0, lb1, lb2, lb3, 3)
  COMPUTE(x2a, x2b, ha0, ha1, ha2, ha3, la0, la1, la2, la3) SBAR
  LOADW(ha0, ha1, ha2, ha3, la0, la1, la2, la3, 4)
  COMPUTE(x3a, x3b, hb0, hb1, hb2, hb3, lb0, lb1, lb2, lb3) SBAR
  LOADW(hb0, hb1, hb2, hb3, lb0, lb1, lb2, lb3, 5)
  COMPUTE(x4a, x4b, ha0, ha1, ha2, ha3, la0, la1, la2, la3) SBAR
  LOADW(ha0, ha1, ha2, ha3, la0, la1, la2, la3, 6)
  COMPUTE(x5a, x5b, hb0, hb1, hb2, hb3, lb0, lb1, lb2, lb3) SBAR
  LOADW(hb0, hb1, hb2, hb3, lb0, lb1, lb2, lb3, 7)
  COMPUTE(x6a, x6b, ha0, ha1, ha2, ha3, la0, la1, la2, la3) SBAR
  COMPUTE(x7a, x7b, hb0, hb1, hb2, hb3, lb0, lb1, lb2, lb3)
#undef LOADW
#undef COMPUTE
#undef SBAR

  // epilogue: lane stores rows (l>>4)*4+reg, cols nf*16 + (l&15), * dinv
#pragma unroll
  for (int reg = 0; reg < 4; reg++) {
    int row = rowbase + (l >> 4) * 4 + reg;
    if (row < NN) {
      float dn = dinv[row];
      unsigned short* hp = (unsigned short*)h + (size_t)row * 64 + (l & 15);
      hp[0]  = f2b(acc0[reg] * dn);
      hp[16] = f2b(acc1[reg] * dn);
      hp[32] = f2b(acc2[reg] * dn);
      hp[48] = f2b(acc3[reg] * dn);
    }
  }
}

// Aggregate v8 (fused sort + gather + MLP): per bucket, LDS sort (per-wave
// sub-histograms), register gather, relu'd row kept in LDS f32 (hrowf,
// stride 65 = conflict-free), then lanes 0..63 run the per-node MLP
// (weights LDS-staged) and write log_softmax directly to out. hg buffer and
// mlp_k launch are gone (-25.6MB traffic, -1 launch); MLP consumes f32
// (un-rounded) -> absmax can only improve.
__global__ __launch_bounds__(512) void agg_k(const bf16* __restrict__ h,
                                             const int* __restrict__ buckets,
                                             const int* __restrict__ bcur,
                                             const float* __restrict__ dinv,
                                             const float* __restrict__ bg,
                                             const float* __restrict__ W1, const float* __restrict__ b1,
                                             const float* __restrict__ W2, const float* __restrict__ b2,
                                             const float* __restrict__ W3, const float* __restrict__ b3,
                                             float* __restrict__ out) {
  __shared__ int ents[CAP];
  __shared__ int srt[CAP];
  __shared__ int cnt8[8][NPB];
  __shared__ int wcur[8][NPB];
  __shared__ int cnt[NPB];
  __shared__ int off[NPB];
  __shared__ float hrowf[NPB][65];       // 16.6 KB, stride-65 conflict-free
  __shared__ float4 sW1f[512];
  __shared__ float4 sW2f[128];
  __shared__ float4 sW3f[16];
  __shared__ float sb1[32], sb2[16], sb3[4];
  int b = blockIdx.x, t = threadIdx.x;
  int w = t >> 6;
  int m = bcur[b]; if (m > CAP) m = CAP;
  const int* bp = buckets + (size_t)b * CAP;
  // stage weights + zero sub-histograms
  if (t < 512) sW1f[t] = ((const float4*)W1)[t];
  if (t < 128) sW2f[t] = ((const float4*)W2)[t];
  if (t < 16)  sW3f[t] = ((const float4*)W3)[t];
  if (t < 32)  sb1[t] = b1[t];
  if (t < 16)  sb2[t] = b2[t];
  if (t < 4)   sb3[t] = b3[t];
  for (int i = t; i < 8 * NPB; i += 512) ((int*)cnt8)[i] = 0;
  __syncthreads();
  for (int i = t; i < m; i += 512) {
    int e = bp[i];
    ents[i] = e;
    atomicAdd(&cnt8[w][(e >> 17) & 63], 1);
  }
  __syncthreads();
  if (t < NPB) {
    int s = 0;
#pragma unroll
    for (int ww = 0; ww < 8; ww++) { int c = cnt8[ww][t]; wcur[ww][t] = s; s += c; }
    cnt[t] = s;
  }
  __syncthreads();
  if (t == 0) {
    int s = 0;
#pragma unroll
    for (int i = 0; i < NPB; i++) { off[i] = s; s += cnt[i]; }
  }
  __syncthreads();
  if (t < NPB) {
#pragma unroll
    for (int ww = 0; ww < 8; ww++) wcur[ww][t] += off[t];
  }
  __syncthreads();
  for (int i = t; i < m; i += 512) {
    int e = ents[i];
    int pos = atomicAdd(&wcur[w][(e >> 17) & 63], 1);
    srt[pos] = e & 0x1FFFF;
  }
  __syncthreads();

  int g = t >> 3, fl = t & 7;
  int node = b * NPB + g;
  bool valid = node < NN;
  int start = valid ? off[g] : 0;
  int deg = valid ? cnt[g] : 0;
  const unsigned short* hu = (const unsigned short*)h;

  float a0 = 0.f, a1 = 0.f, a2 = 0.f, a3 = 0.f,
        a4 = 0.f, a5 = 0.f, a6 = 0.f, a7 = 0.f;

#define ACCV(V)                                                          \
  {                                                                      \
    a0 += __uint_as_float(V.x << 16); a1 += __uint_as_float(V.x & 0xFFFF0000u); \
    a2 += __uint_as_float(V.y << 16); a3 += __uint_as_float(V.y & 0xFFFF0000u); \
    a4 += __uint_as_float(V.z << 16); a5 += __uint_as_float(V.z & 0xFFFF0000u); \
    a6 += __uint_as_float(V.w << 16); a7 += __uint_as_float(V.w & 0xFFFF0000u); \
  }

  int i = 0;
  for (; i + 4 <= deg; i += 4) {
    int s0 = srt[start + i], s1 = srt[start + i + 1];
    int s2 = srt[start + i + 2], s3 = srt[start + i + 3];
    uint4 v0 = *(const uint4*)(hu + (size_t)s0 * 64 + fl * 8);
    uint4 v1 = *(const uint4*)(hu + (size_t)s1 * 64 + fl * 8);
    uint4 v2 = *(const uint4*)(hu + (size_t)s2 * 64 + fl * 8);
    uint4 v3 = *(const uint4*)(hu + (size_t)s3 * 64 + fl * 8);
    ACCV(v0) ACCV(v1) ACCV(v2) ACCV(v3)
  }
  for (; i < deg; i++) {
    int s0 = srt[start + i];
    uint4 v0 = *(const uint4*)(hu + (size_t)s0 * 64 + fl * 8);
    ACCV(v0)
  }
#undef ACCV

  // epilogue: relu((sum + self) * dn + bias) -> LDS f32 row
  if (valid) {
    float dn = dinv[node];
    uint4 sv = *(const uint4*)(hu + (size_t)node * 64 + fl * 8);
    const float* bb = bg + fl * 8;
    a0 += __uint_as_float(sv.x << 16); a1 += __uint_as_float(sv.x & 0xFFFF0000u);
    a2 += __uint_as_float(sv.y << 16); a3 += __uint_as_float(sv.y & 0xFFFF0000u);
    a4 += __uint_as_float(sv.z << 16); a5 += __uint_as_float(sv.z & 0xFFFF0000u);
    a6 += __uint_as_float(sv.w << 16); a7 += __uint_as_float(sv.w & 0xFFFF0000u);
    float* hr = &hrowf[g][fl * 8];
    hr[0] = fmaxf(fmaf(a0, dn, bb[0]), 0.f);
    hr[1] = fmaxf(fmaf(a1, dn, bb[1]), 0.f);
    hr[2] = fmaxf(fmaf(a2, dn, bb[2]), 0.f);
    hr[3] = fmaxf(fmaf(a3, dn, bb[3]), 0.f);
    hr[4] = fmaxf(fmaf(a4, dn, bb[4]), 0.f);
    hr[5] = fmaxf(fmaf(a5, dn, bb[5]), 0.f);
    hr[6] = fmaxf(fmaf(a6, dn, bb[6]), 0.f);
    hr[7] = fmaxf(fmaf(a7, dn, bb[7]), 0.f);
  }
  __syncthreads();

  // ---- fused MLP: one lane per node (t<64), weights from LDS (broadcast),
  // inputs from hrowf[t][*] (stride-65, conflict-free across lanes).
  if (t < 64) {
    int nodem = b * NPB + t;
    if (nodem < NN) {
      float4 m1[8];
#pragma unroll
      for (int j = 0; j < 8; j++)
        m1[j] = make_float4(sb1[4 * j], sb1[4 * j + 1], sb1[4 * j + 2], sb1[4 * j + 3]);
#pragma unroll
      for (int f = 0; f < 64; f++) {
        float xv = hrowf[t][f];
#pragma unroll
        for (int j = 0; j < 8; j++) fma4(m1[j], xv, sW1f[f * 8 + j]);
      }
      float r2[32];
#pragma unroll
      for (int j = 0; j < 8; j++) {
        r2[4 * j + 0] = fmaxf(m1[j].x, 0.f);
        r2[4 * j + 1] = fmaxf(m1[j].y, 0.f);
        r2[4 * j + 2] = fmaxf(m1[j].z, 0.f);
        r2[4 * j + 3] = fmaxf(m1[j].w, 0.f);
      }
      float4 m2[4];
#pragma unroll
      for (int j = 0; j < 4; j++)
        m2[j] = make_float4(sb2[4 * j], sb2[4 * j + 1], sb2[4 * j + 2], sb2[4 * j + 3]);
#pragma unroll
      for (int f = 0; f < 32; f++) {
        float xv = r2[f];
#pragma unroll
        for (int j = 0; j < 4; j++) fma4(m2[j], xv, sW2f[f * 4 + j]);
      }
      float r3[16];
#pragma unroll
      for (int j = 0; j < 4; j++) {
        r3[4 * j + 0] = fmaxf(m2[j].x, 0.f);
        r3[4 * j + 1] = fmaxf(m2[j].y, 0.f);
        r3[4 * j + 2] = fmaxf(m2[j].z, 0.f);
        r3[4 * j + 3] = fmaxf(m2[j].w, 0.f);
      }
      float4 m3 = make_float4(sb3[0], sb3[1], sb3[2], sb3[3]);
#pragma unroll
      for (int f = 0; f < 16; f++) fma4(m3, r3[f], sW3f[f]);
      float mx = fmaxf(fmaxf(m3.x, m3.y), fmaxf(m3.z, m3.w));
      float s = expf(m3.x - mx) + expf(m3.y - mx) + expf(m3.z - mx) + expf(m3.w - mx);
      float lg = mx + logf(s);
      ((float4*)out)[nodem] = make_float4(m3.x - lg, m3.y - lg, m3.z - lg, m3.w - lg);
    }
  }
}

extern "C" void kernel_launch(void* const* d_in, const int* in_sizes, int n_in,
                              void* d_out, int out_size, void* d_ws, size_t ws_size,
                              hipStream_t stream) {
  const float* x  = (const float*)d_in[0];
  const void* eidx = d_in[1];
  const float* Wg = (const float*)d_in[2];
  const float* bg = (const float*)d_in[3];
  const float* W1 = (const float*)d_in[4];
  const float* b1 = (const float*)d_in[5];
  const float* W2 = (const float*)d_in[6];
  const float* b2 = (const float*)d_in[7];
  const float* W3 = (const float*)d_in[8];
  const float* b3 = (const float*)d_in[9];

  char* ws = (char*)d_ws;
  bf16*  h       = (bf16*) (ws + 0);           // 12,800,000 B
  int*   buckets = (int*)  (ws + 25600000);    // 1564*2560*4 = 16,015,360 B
  float* dinv    = (float*)(ws + 41615360);    //    400,000 B
  int*   bcur    = (int*)  (ws + 42415360);    //      6,256 B
  // wh/wl (32KB each) in the unused former-hg region.
  unsigned short* wh = (unsigned short*)(ws + 12800000);
  unsigned short* wl = (unsigned short*)(ws + 12800000 + 32768);

  hipMemsetAsync(bcur, 0, NB * sizeof(int), stream);
  bin_k<<<(NE + BATCH - 1) / BATCH, 1024, 0, stream>>>(eidx, bcur, buckets);
  cnt_k<<<NB + 1, 256, 0, stream>>>(buckets, bcur, dinv, Wg, wh, wl);
  gemm_k<<<NGB, 256, 0, stream>>>(x, wh, wl, dinv, h);
  agg_k<<<NB, 512, 0, stream>>>(h, buckets, bcur, dinv, bg, W1, b1, W2, b2, W3, b3, (float*)d_out);
}

// Round 14
// 158.435 us; speedup vs baseline: 1.1178x; 1.1178x over previous
//
#include <hip/hip_runtime.h>
#include <hip/hip_bf16.h>

#define NN 100000
#define NE 3200000
#define NPB 64        // dst nodes per bucket
#define NB 1564       // 1564*64 = 100096 >= NN
#define CAP 2560      // mean 2046, sigma ~45 -> +11 sigma headroom
#define BATCH 4096    // edges staged per bin_k block (58KB LDS -> 2 blk/CU)
#define NGB 1563      // gemm blocks: 1563*64 = 100032 >= NN

typedef __hip_bfloat16 bf16;
typedef __attribute__((ext_vector_type(8))) short bf16x8;  // 8 bf16 (4 VGPR)
typedef __attribute__((ext_vector_type(4))) float f32x4;

__device__ __forceinline__ void fma4(float4& a, float s, const float4 w) {
  a.x = fmaf(s, w.x, a.x);
  a.y = fmaf(s, w.y, a.y);
  a.z = fmaf(s, w.z, a.z);
  a.w = fmaf(s, w.w, a.w);
}

__device__ __forceinline__ unsigned short f2b(float f) {  // f32 -> bf16 RNE
  unsigned u = __float_as_uint(f);
  unsigned r = ((u >> 16) & 1u) + 0x7FFFu;
  return (unsigned short)((u + r) >> 16);
}

__device__ __forceinline__ unsigned pack2(float lo, float hi) {
  return (unsigned)f2b(lo) | ((unsigned)f2b(hi) << 16);
}

// Binning v4: inline detect (wave-0 ballot). LDS histogram -> bulk global
// range reservation -> LDS bucket-sort -> coalesced ordered write-out.
// BATCH 4096 -> 58KB LDS -> 2 blocks/CU (32 waves, was 1 blk/16 waves at
// 8192/89KB). Cost: 2x bcur atomics (1.2M over 1564 hot L2 addrs, ~+2us).
__global__ __launch_bounds__(1024) void bin_k(const void* __restrict__ eidx,
                                              int* __restrict__ bcur,
                                              int* __restrict__ buckets) {
  __shared__ int scnt[NB];
  __shared__ int sofs[NB];      // LDS run start
  __shared__ int sbase[NB];     // global run start (this block's reservation)
  __shared__ int lcur[NB];      // LDS scatter cursor
  __shared__ int tot;
  __shared__ int sflag;
  __shared__ int sorted[BATCH]; // 16 KB
  __shared__ int gaddr[BATCH];  // 16 KB
  int t = threadIdx.x;
  long long e0 = (long long)blockIdx.x * BATCH;
  int m = (int)((NE - e0 < BATCH) ? (NE - e0) : BATCH);

  // inline detect: int64 iff high dwords of first 64 values are all zero
  if (t < 64) {
    unsigned long long bb = __ballot(((const int*)eidx)[2 * t + 1] == 0);
    if (t == 0) sflag = (bb == 0xFFFFFFFFFFFFFFFFULL) ? 1 : 0;
  }
  for (int i = t; i < NB; i += 1024) scnt[i] = 0;
  if (t == 0) tot = 0;
  __syncthreads();
  int isI64 = sflag;

  int ent[BATCH / 1024], bv[BATCH / 1024];
#pragma unroll
  for (int j = 0; j < BATCH / 1024; j++) {
    int idx = t + j * 1024;
    bv[j] = -1;
    if (idx < m) {
      long long i = e0 + idx;
      int s, d;
      if (isI64) {
        s = (int)((const long long*)eidx)[i];
        d = (int)((const long long*)eidx)[NE + i];
      } else {
        s = ((const int*)eidx)[i];
        d = ((const int*)eidx)[NE + i];
      }
      bv[j] = d >> 6;
      ent[j] = s | ((d & 63) << 17);
      atomicAdd(&scnt[bv[j]], 1);
    }
  }
  __syncthreads();
  for (int i = t; i < NB; i += 1024) {
    int c = scnt[i];
    if (c) {
      sofs[i] = atomicAdd(&tot, c);
      sbase[i] = atomicAdd(&bcur[i], c);
      lcur[i] = sofs[i];
    }
  }
  __syncthreads();
#pragma unroll
  for (int j = 0; j < BATCH / 1024; j++) {
    if (bv[j] >= 0) {
      int pos = atomicAdd(&lcur[bv[j]], 1);
      sorted[pos] = ent[j];
      int gp = sbase[bv[j]] + (pos - sofs[bv[j]]);
      gaddr[pos] = (gp < CAP) ? bv[j] * CAP + gp : -1;
    }
  }
  __syncthreads();
  for (int i = t; i < m; i += 1024) {
    int ga = gaddr[i];
    if (ga >= 0) buckets[ga] = sorted[i];
  }
}

// cnt-lite + prep fused: blocks 0..NB-1 do the per-bucket histogram -> dinv
// (4-wave sub-histograms, no same-address contention); block NB converts W
// into MFMA-fragment-ordered bf16 hi/lo.
__global__ __launch_bounds__(256) void cnt_k(const int* __restrict__ buckets,
                                             const int* __restrict__ bcur,
                                             float* __restrict__ dinv,
                                             const float* __restrict__ W,
                                             unsigned short* __restrict__ wh,
                                             unsigned short* __restrict__ wl) {
  int b = blockIdx.x, t = threadIdx.x;
  if (b == NB) {   // ---- prep: W -> wh/wl fragment-ordered bf16 hi/lo
#pragma unroll 4
    for (int i = 0; i < 64; i++) {
      int idx = i * 256 + t;
      int j = idx & 7;
      int lane = (idx >> 3) & 63;
      int pair = idx >> 9;           // kk*4 + nf
      int nf = pair & 3, kk = pair >> 2;
      int k = kk * 32 + (lane >> 4) * 8 + j;
      int n = nf * 16 + (lane & 15);
      float w = W[k * 64 + n];
      unsigned short hh = f2b(w);
      float fh = __uint_as_float((unsigned)hh << 16);
      wh[idx] = hh;
      wl[idx] = f2b(w - fh);
    }
    return;
  }
  __shared__ int c4[4][NPB];
  int w = t >> 6;
  if (t < 128) { c4[0][t & 63] = 0; c4[1][t & 63] = 0; }
  else         { c4[2][t & 63] = 0; c4[3][t & 63] = 0; }
  __syncthreads();
  int m = bcur[b]; if (m > CAP) m = CAP;
  const int* bp = buckets + (size_t)b * CAP;
  for (int i = t; i < m; i += 256) atomicAdd(&c4[w][(bp[i] >> 17) & 63], 1);
  __syncthreads();
  int node = b * NPB + t;
  if (t < NPB && node < NN) {
    int s = c4[0][t] + c4[1][t] + c4[2][t] + c4[3][t];
    dinv[node] = rsqrtf((float)s + 1.0f);
  }
}

// h' = (x @ W_gcn) * dinv[row], bf16 out (dinv baked in).
// v13 (MFMA, full-row x preload): per lane the entire 64-float x window is
// issued as 16 upfront global_load_dwordx4; W frags register double-buffered
// one step ahead; sched_barrier(0) fences between steps cap the live set.
// acc += xh*Wh + xh*Wl + xl*Wh (f32 acc; error ~2^-17, numerically == f32).
// C/D layout (m89-verified): col=lane&15, row=(l>>4)*4+reg.
__global__ __launch_bounds__(256) void gemm_k(const float* __restrict__ x,
                                              const unsigned short* __restrict__ wh,
                                              const unsigned short* __restrict__ wl,
                                              const float* __restrict__ dinv,
                                              bf16* __restrict__ h) {
  int t = threadIdx.x;
  int wv = t >> 6, l = t & 63;
  int rowbase = blockIdx.x * 64 + wv * 16;
  int arow = rowbase + (l & 15);
  if (arow >= NN) arow = NN - 1;           // clamp loads, mask stores
  const float* xrow = x + (size_t)arow * 256 + (l >> 4) * 8;

  const bf16x8* whf = (const bf16x8*)wh;   // [ (kk*4+nf)*64 + lane ]
  const bf16x8* wlf = (const bf16x8*)wl;

  f32x4 acc0 = {0.f, 0.f, 0.f, 0.f};
  f32x4 acc1 = acc0, acc2 = acc0, acc3 = acc0;

  // -------- preload the lane's whole x window (16 dwordx4, all in flight)
  float4 x0a = *(const float4*)(xrow +   0), x0b = *(const float4*)(xrow +   4);
  float4 x1a = *(const float4*)(xrow +  32), x1b = *(const float4*)(xrow +  36);
  float4 x2a = *(const float4*)(xrow +  64), x2b = *(const float4*)(xrow +  68);
  float4 x3a = *(const float4*)(xrow +  96), x3b = *(const float4*)(xrow + 100);
  float4 x4a = *(const float4*)(xrow + 128), x4b = *(const float4*)(xrow + 132);
  float4 x5a = *(const float4*)(xrow + 160), x5b = *(const float4*)(xrow + 164);
  float4 x6a = *(const float4*)(xrow + 192), x6b = *(const float4*)(xrow + 196);
  float4 x7a = *(const float4*)(xrow + 224), x7b = *(const float4*)(xrow + 228);

  bf16x8 ha0, ha1, ha2, ha3, la0, la1, la2, la3;   // W set A
  bf16x8 hb0, hb1, hb2, hb3, lb0, lb1, lb2, lb3;   // W set B

#define LOADW(H0, H1, H2, H3, L0, L1, L2, L3, kk)                      \
  {                                                                    \
    int fb_ = (kk) * 256 + l;                                          \
    H0 = whf[fb_]; H1 = whf[fb_ + 64]; H2 = whf[fb_ + 128]; H3 = whf[fb_ + 192]; \
    L0 = wlf[fb_]; L1 = wlf[fb_ + 64]; L2 = wlf[fb_ + 128]; L3 = wlf[fb_ + 192]; \
  }
#define COMPUTE(Xa, Xb, H0, H1, H2, H3, L0, L1, L2, L3)                \
  {                                                                    \
    bf16x8 ah, al;                                                     \
    {                                                                  \
      unsigned short hh_; float fh_;                                   \
      hh_ = f2b(Xa.x); fh_ = __uint_as_float((unsigned)hh_ << 16); ah[0] = (short)hh_; al[0] = (short)f2b(Xa.x - fh_); \
      hh_ = f2b(Xa.y); fh_ = __uint_as_float((unsigned)hh_ << 16); ah[1] = (short)hh_; al[1] = (short)f2b(Xa.y - fh_); \
      hh_ = f2b(Xa.z); fh_ = __uint_as_float((unsigned)hh_ << 16); ah[2] = (short)hh_; al[2] = (short)f2b(Xa.z - fh_); \
      hh_ = f2b(Xa.w); fh_ = __uint_as_float((unsigned)hh_ << 16); ah[3] = (short)hh_; al[3] = (short)f2b(Xa.w - fh_); \
      hh_ = f2b(Xb.x); fh_ = __uint_as_float((unsigned)hh_ << 16); ah[4] = (short)hh_; al[4] = (short)f2b(Xb.x - fh_); \
      hh_ = f2b(Xb.y); fh_ = __uint_as_float((unsigned)hh_ << 16); ah[5] = (short)hh_; al[5] = (short)f2b(Xb.y - fh_); \
      hh_ = f2b(Xb.z); fh_ = __uint_as_float((unsigned)hh_ << 16); ah[6] = (short)hh_; al[6] = (short)f2b(Xb.z - fh_); \
      hh_ = f2b(Xb.w); fh_ = __uint_as_float((unsigned)hh_ << 16); ah[7] = (short)hh_; al[7] = (short)f2b(Xb.w - fh_); \
    }                                                                  \
    acc0 = __builtin_amdgcn_mfma_f32_16x16x32_bf16(ah, H0, acc0, 0, 0, 0); \
    acc1 = __builtin_amdgcn_mfma_f32_16x16x32_bf16(ah, H1, acc1, 0, 0, 0); \
    acc2 = __builtin_amdgcn_mfma_f32_16x16x32_bf16(ah, H2, acc2, 0, 0, 0); \
    acc3 = __builtin_amdgcn_mfma_f32_16x16x32_bf16(ah, H3, acc3, 0, 0, 0); \
    acc0 = __builtin_amdgcn_mfma_f32_16x16x32_bf16(ah, L0, acc0, 0, 0, 0); \
    acc1 = __builtin_amdgcn_mfma_f32_16x16x32_bf16(ah, L1, acc1, 0, 0, 0); \
    acc2 = __builtin_amdgcn_mfma_f32_16x16x32_bf16(ah, L2, acc2, 0, 0, 0); \
    acc3 = __builtin_amdgcn_mfma_f32_16x16x32_bf16(ah, L3, acc3, 0, 0, 0); \
    acc0 = __builtin_amdgcn_mfma_f32_16x16x32_bf16(al, H0, acc0, 0, 0, 0); \
    acc1 = __builtin_amdgcn_mfma_f32_16x16x32_bf16(al, H1, acc1, 0, 0, 0); \
    acc2 = __builtin_amdgcn_mfma_f32_16x16x32_bf16(al, H2, acc2, 0, 0, 0); \
    acc3 = __builtin_amdgcn_mfma_f32_16x16x32_bf16(al, H3, acc3, 0, 0, 0); \
  }
#define SBAR __builtin_amdgcn_sched_barrier(0);

  LOADW(ha0, ha1, ha2, ha3, la0, la1, la2, la3, 0)
  LOADW(hb0, hb1, hb2, hb3, lb0, lb1, lb2, lb3, 1)
  COMPUTE(x0a, x0b, ha0, ha1, ha2, ha3, la0, la1, la2, la3) SBAR
  LOADW(ha0, ha1, ha2, ha3, la0, la1, la2, la3, 2)
  COMPUTE(x1a, x1b, hb0, hb1, hb2, hb3, lb0, lb1, lb2, lb3) SBAR
  LOADW(hb0, hb1, hb2, hb3, lb0, lb1, lb2, lb3, 3)
  COMPUTE(x2a, x2b, ha0, ha1, ha2, ha3, la0, la1, la2, la3) SBAR
  LOADW(ha0, ha1, ha2, ha3, la0, la1, la2, la3, 4)
  COMPUTE(x3a, x3b, hb0, hb1, hb2, hb3, lb0, lb1, lb2, lb3) SBAR
  LOADW(hb0, hb1, hb2, hb3, lb0, lb1, lb2, lb3, 5)
  COMPUTE(x4a, x4b, ha0, ha1, ha2, ha3, la0, la1, la2, la3) SBAR
  LOADW(ha0, ha1, ha2, ha3, la0, la1, la2, la3, 6)
  COMPUTE(x5a, x5b, hb0, hb1, hb2, hb3, lb0, lb1, lb2, lb3) SBAR
  LOADW(hb0, hb1, hb2, hb3, lb0, lb1, lb2, lb3, 7)
  COMPUTE(x6a, x6b, ha0, ha1, ha2, ha3, la0, la1, la2, la3) SBAR
  COMPUTE(x7a, x7b, hb0, hb1, hb2, hb3, lb0, lb1, lb2, lb3)
#undef LOADW
#undef COMPUTE
#undef SBAR

  // epilogue: lane stores rows (l>>4)*4+reg, cols nf*16 + (l&15), * dinv
#pragma unroll
  for (int reg = 0; reg < 4; reg++) {
    int row = rowbase + (l >> 4) * 4 + reg;
    if (row < NN) {
      float dn = dinv[row];
      unsigned short* hp = (unsigned short*)h + (size_t)row * 64 + (l & 15);
      hp[0]  = f2b(acc0[reg] * dn);
      hp[16] = f2b(acc1[reg] * dn);
      hp[32] = f2b(acc2[reg] * dn);
      hp[48] = f2b(acc3[reg] * dn);
    }
  }
}

// Aggregate v7 (fused sort + gather, per-wave histograms/cursors): the
// histogram and scatter passes use per-wave sub-bins (cnt8/wcur[8][64]) so
// same-address LDS atomic contention drops ~8x. LDS ~25KB -> 4 blocks/CU
// (thread-capped) = full occupancy; round 13 proved agg is occupancy-
// sensitive (latency-bound random gathers), so no MLP fusion here.
__global__ __launch_bounds__(512) void agg_k(const bf16* __restrict__ h,
                                             const int* __restrict__ buckets,
                                             const int* __restrict__ bcur,
                                             const float* __restrict__ dinv,
                                             const float* __restrict__ bg,
                                             bf16* __restrict__ hg) {
  __shared__ int ents[CAP];
  __shared__ int srt[CAP];
  __shared__ int cnt8[8][NPB];
  __shared__ int wcur[8][NPB];
  __shared__ int cnt[NPB];
  __shared__ int off[NPB];
  int b = blockIdx.x, t = threadIdx.x;
  int w = t >> 6;
  int m = bcur[b]; if (m > CAP) m = CAP;
  const int* bp = buckets + (size_t)b * CAP;
  for (int i = t; i < 8 * NPB; i += 512) ((int*)cnt8)[i] = 0;
  __syncthreads();
  for (int i = t; i < m; i += 512) {
    int e = bp[i];
    ents[i] = e;
    atomicAdd(&cnt8[w][(e >> 17) & 63], 1);
  }
  __syncthreads();
  if (t < NPB) {
    int s = 0;
#pragma unroll
    for (int ww = 0; ww < 8; ww++) { int c = cnt8[ww][t]; wcur[ww][t] = s; s += c; }
    cnt[t] = s;
  }
  __syncthreads();
  if (t == 0) {
    int s = 0;
#pragma unroll
    for (int i = 0; i < NPB; i++) { off[i] = s; s += cnt[i]; }
  }
  __syncthreads();
  if (t < NPB) {
#pragma unroll
    for (int ww = 0; ww < 8; ww++) wcur[ww][t] += off[t];
  }
  __syncthreads();
  for (int i = t; i < m; i += 512) {
    int e = ents[i];
    int pos = atomicAdd(&wcur[w][(e >> 17) & 63], 1);
    srt[pos] = e & 0x1FFFF;
  }
  __syncthreads();

  int g = t >> 3, fl = t & 7;
  int node = b * NPB + g;
  if (node >= NN) return;
  int start = off[g];
  int deg = cnt[g];
  float dn = dinv[node];
  const unsigned short* hu = (const unsigned short*)h;

  float a0 = 0.f, a1 = 0.f, a2 = 0.f, a3 = 0.f,
        a4 = 0.f, a5 = 0.f, a6 = 0.f, a7 = 0.f;

#define ACCV(V)                                                          \
  {                                                                      \
    a0 += __uint_as_float(V.x << 16); a1 += __uint_as_float(V.x & 0xFFFF0000u); \
    a2 += __uint_as_float(V.y << 16); a3 += __uint_as_float(V.y & 0xFFFF0000u); \
    a4 += __uint_as_float(V.z << 16); a5 += __uint_as_float(V.z & 0xFFFF0000u); \
    a6 += __uint_as_float(V.w << 16); a7 += __uint_as_float(V.w & 0xFFFF0000u); \
  }

  int i = 0;
  for (; i + 4 <= deg; i += 4) {
    int s0 = srt[start + i], s1 = srt[start + i + 1];
    int s2 = srt[start + i + 2], s3 = srt[start + i + 3];
    uint4 v0 = *(const uint4*)(hu + (size_t)s0 * 64 + fl * 8);
    uint4 v1 = *(const uint4*)(hu + (size_t)s1 * 64 + fl * 8);
    uint4 v2 = *(const uint4*)(hu + (size_t)s2 * 64 + fl * 8);
    uint4 v3 = *(const uint4*)(hu + (size_t)s3 * 64 + fl * 8);
    ACCV(v0) ACCV(v1) ACCV(v2) ACCV(v3)
  }
  for (; i < deg; i++) {
    int s0 = srt[start + i];
    uint4 v0 = *(const uint4*)(hu + (size_t)s0 * 64 + fl * 8);
    ACCV(v0)
  }
#undef ACCV

  // epilogue: out = relu( (sum + self) * dn + bias ), bf16 store
  uint4 sv = *(const uint4*)(hu + (size_t)node * 64 + fl * 8);
  const float* bb = bg + fl * 8;
  a0 += __uint_as_float(sv.x << 16); a1 += __uint_as_float(sv.x & 0xFFFF0000u);
  a2 += __uint_as_float(sv.y << 16); a3 += __uint_as_float(sv.y & 0xFFFF0000u);
  a4 += __uint_as_float(sv.z << 16); a5 += __uint_as_float(sv.z & 0xFFFF0000u);
  a6 += __uint_as_float(sv.w << 16); a7 += __uint_as_float(sv.w & 0xFFFF0000u);
  uint4 o;
  o.x = pack2(fmaxf(fmaf(a0, dn, bb[0]), 0.f), fmaxf(fmaf(a1, dn, bb[1]), 0.f));
  o.y = pack2(fmaxf(fmaf(a2, dn, bb[2]), 0.f), fmaxf(fmaf(a3, dn, bb[3]), 0.f));
  o.z = pack2(fmaxf(fmaf(a4, dn, bb[4]), 0.f), fmaxf(fmaf(a5, dn, bb[5]), 0.f));
  o.w = pack2(fmaxf(fmaf(a6, dn, bb[6]), 0.f), fmaxf(fmaf(a7, dn, bb[7]), 0.f));
  *(uint4*)((unsigned short*)hg + (size_t)node * 64 + fl * 8) = o;
}

// Per-thread node MLP: 64 -> 32 -> 16 -> 4 + log_softmax.
__global__ __launch_bounds__(256) void mlp_k(const bf16* __restrict__ hg,
                                             const float* __restrict__ W1, const float* __restrict__ b1,
                                             const float* __restrict__ W2, const float* __restrict__ b2,
                                             const float* __restrict__ W3, const float* __restrict__ b3,
                                             float* __restrict__ out) {
  __shared__ float4 sW1[512];
  __shared__ float4 sW2[128];
  __shared__ float4 sW3[16];
  __shared__ float sb1[32], sb2[16], sb3[4];
  int t = threadIdx.x;
  for (int i = t; i < 512; i += 256) sW1[i] = ((const float4*)W1)[i];
  if (t < 128) sW2[t] = ((const float4*)W2)[t];
  if (t < 16)  sW3[t] = ((const float4*)W3)[t];
  if (t < 32)  sb1[t] = b1[t];
  if (t < 16)  sb2[t] = b2[t];
  if (t < 4)   sb3[t] = b3[t];
  __syncthreads();
  int n = blockIdx.x * 256 + t;
  if (n >= NN) return;
  float xr[64];
  const uint4* hp = (const uint4*)(hg + (size_t)n * 64);
#pragma unroll
  for (int i = 0; i < 8; i++) {
    uint4 v = hp[i];
    unsigned uu[4] = {v.x, v.y, v.z, v.w};
#pragma unroll
    for (int j = 0; j < 4; j++) {
      xr[8 * i + 2 * j]     = __uint_as_float(uu[j] << 16);
      xr[8 * i + 2 * j + 1] = __uint_as_float(uu[j] & 0xFFFF0000u);
    }
  }
  float4 a1[8];
#pragma unroll
  for (int j = 0; j < 8; j++) a1[j] = make_float4(sb1[4 * j], sb1[4 * j + 1], sb1[4 * j + 2], sb1[4 * j + 3]);
#pragma unroll
  for (int f = 0; f < 64; f++) {
    float xv = xr[f];
#pragma unroll
    for (int j = 0; j < 8; j++) fma4(a1[j], xv, sW1[f * 8 + j]);
  }
  float r2[32];
#pragma unroll
  for (int j = 0; j < 8; j++) {
    r2[4 * j + 0] = fmaxf(a1[j].x, 0.f);
    r2[4 * j + 1] = fmaxf(a1[j].y, 0.f);
    r2[4 * j + 2] = fmaxf(a1[j].z, 0.f);
    r2[4 * j + 3] = fmaxf(a1[j].w, 0.f);
  }
  float4 a2[4];
#pragma unroll
  for (int j = 0; j < 4; j++) a2[j] = make_float4(sb2[4 * j], sb2[4 * j + 1], sb2[4 * j + 2], sb2[4 * j + 3]);
#pragma unroll
  for (int f = 0; f < 32; f++) {
    float xv = r2[f];
#pragma unroll
    for (int j = 0; j < 4; j++) fma4(a2[j], xv, sW2[f * 4 + j]);
  }
  float r3[16];
#pragma unroll
  for (int j = 0; j < 4; j++) {
    r3[4 * j + 0] = fmaxf(a2[j].x, 0.f);
    r3[4 * j + 1] = fmaxf(a2[j].y, 0.f);
    r3[4 * j + 2] = fmaxf(a2[j].z, 0.f);
    r3[4 * j + 3] = fmaxf(a2[j].w, 0.f);
  }
  float4 a3 = make_float4(sb3[0], sb3[1], sb3[2], sb3[3]);
#pragma unroll
  for (int f = 0; f < 16; f++) fma4(a3, r3[f], sW3[f]);
  float m = fmaxf(fmaxf(a3.x, a3.y), fmaxf(a3.z, a3.w));
  float s = expf(a3.x - m) + expf(a3.y - m) + expf(a3.z - m) + expf(a3.w - m);
  float l = m + logf(s);
  ((float4*)out)[n] = make_float4(a3.x - l, a3.y - l, a3.z - l, a3.w - l);
}

extern "C" void kernel_launch(void* const* d_in, const int* in_sizes, int n_in,
                              void* d_out, int out_size, void* d_ws, size_t ws_size,
                              hipStream_t stream) {
  const float* x  = (const float*)d_in[0];
  const void* eidx = d_in[1];
  const float* Wg = (const float*)d_in[2];
  const float* bg = (const float*)d_in[3];
  const float* W1 = (const float*)d_in[4];
  const float* b1 = (const float*)d_in[5];
  const float* W2 = (const float*)d_in[6];
  const float* b2 = (const float*)d_in[7];
  const float* W3 = (const float*)d_in[8];
  const float* b3 = (const float*)d_in[9];

  char* ws = (char*)d_ws;
  bf16*  h       = (bf16*) (ws + 0);           // 12,800,000 B
  bf16*  hg      = (bf16*) (ws + 12800000);    // 12,800,000 B
  int*   buckets = (int*)  (ws + 25600000);    // 1564*2560*4 = 16,015,360 B
  float* dinv    = (float*)(ws + 41615360);    //    400,000 B
  int*   bcur    = (int*)  (ws + 42415360);    //      6,256 B
  // wh/wl (32KB each) live in the hg region: hg is only WRITTEN by agg_k,
  // which runs after gemm_k has finished reading wh/wl (stream-ordered).
  unsigned short* wh = (unsigned short*)(ws + 12800000);
  unsigned short* wl = (unsigned short*)(ws + 12800000 + 32768);

  hipMemsetAsync(bcur, 0, NB * sizeof(int), stream);
  bin_k<<<(NE + BATCH - 1) / BATCH, 1024, 0, stream>>>(eidx, bcur, buckets);
  cnt_k<<<NB + 1, 256, 0, stream>>>(buckets, bcur, dinv, Wg, wh, wl);
  gemm_k<<<NGB, 256, 0, stream>>>(x, wh, wl, dinv, h);
  agg_k<<<NB, 512, 0, stream>>>(h, buckets, bcur, dinv, bg, hg);
  mlp_k<<<(NN + 255) / 256, 256, 0, stream>>>(hg, W1, b1, W2, b2, W3, b3, (float*)d_out);
}

// Round 15
// 152.207 us; speedup vs baseline: 1.1636x; 1.0409x over previous
//
#include <hip/hip_runtime.h>
#include <hip/hip_bf16.h>

#define NN 100000
#define NE 3200000
#define NPB 64        // dst nodes per bucket
#define NB 1564       // 1564*64 = 100096 >= NN
#define CAP 2560      // mean 2046, sigma ~45 -> +11 sigma headroom
#define BATCH 8192    // edges staged per bin_k block (measured optimum vs 4096)
#define NGB 1563      // gemm blocks: 1563*64 = 100032 >= NN

typedef __hip_bfloat16 bf16;
typedef __attribute__((ext_vector_type(8))) short bf16x8;  // 8 bf16 (4 VGPR)
typedef __attribute__((ext_vector_type(4))) float f32x4;

__device__ __forceinline__ void fma4(float4& a, float s, const float4 w) {
  a.x = fmaf(s, w.x, a.x);
  a.y = fmaf(s, w.y, a.y);
  a.z = fmaf(s, w.z, a.z);
  a.w = fmaf(s, w.w, a.w);
}

__device__ __forceinline__ unsigned short f2b(float f) {  // f32 -> bf16 RNE
  unsigned u = __float_as_uint(f);
  unsigned r = ((u >> 16) & 1u) + 0x7FFFu;
  return (unsigned short)((u + r) >> 16);
}

__device__ __forceinline__ unsigned pack2(float lo, float hi) {
  return (unsigned)f2b(lo) | ((unsigned)f2b(hi) << 16);
}

// Binning v3: detect folded in (wave-0 ballot per block). LDS histogram ->
// bulk global range reservation -> LDS bucket-sort -> coalesced write-out.
// BATCH 8192 measured faster than 4096 (per-block fixed work + reservation
// atomics dominate over occupancy for this kernel -- round 14).
__global__ __launch_bounds__(1024) void bin_k(const void* __restrict__ eidx,
                                              int* __restrict__ bcur,
                                              int* __restrict__ buckets) {
  __shared__ int scnt[NB];
  __shared__ int sofs[NB];      // LDS run start
  __shared__ int sbase[NB];     // global run start (this block's reservation)
  __shared__ int lcur[NB];      // LDS scatter cursor
  __shared__ int tot;
  __shared__ int sflag;
  __shared__ int sorted[BATCH]; // 32 KB
  __shared__ int gaddr[BATCH];  // 32 KB
  int t = threadIdx.x;
  long long e0 = (long long)blockIdx.x * BATCH;
  int m = (int)((NE - e0 < BATCH) ? (NE - e0) : BATCH);

  // inline detect: int64 iff high dwords of first 64 values are all zero
  if (t < 64) {
    unsigned long long bb = __ballot(((const int*)eidx)[2 * t + 1] == 0);
    if (t == 0) sflag = (bb == 0xFFFFFFFFFFFFFFFFULL) ? 1 : 0;
  }
  for (int i = t; i < NB; i += 1024) scnt[i] = 0;
  if (t == 0) tot = 0;
  __syncthreads();
  int isI64 = sflag;

  int ent[BATCH / 1024], bv[BATCH / 1024];
#pragma unroll
  for (int j = 0; j < BATCH / 1024; j++) {
    int idx = t + j * 1024;
    bv[j] = -1;
    if (idx < m) {
      long long i = e0 + idx;
      int s, d;
      if (isI64) {
        s = (int)((const long long*)eidx)[i];
        d = (int)((const long long*)eidx)[NE + i];
      } else {
        s = ((const int*)eidx)[i];
        d = ((const int*)eidx)[NE + i];
      }
      bv[j] = d >> 6;
      ent[j] = s | ((d & 63) << 17);
      atomicAdd(&scnt[bv[j]], 1);
    }
  }
  __syncthreads();
  for (int i = t; i < NB; i += 1024) {
    int c = scnt[i];
    if (c) {
      sofs[i] = atomicAdd(&tot, c);
      sbase[i] = atomicAdd(&bcur[i], c);
      lcur[i] = sofs[i];
    }
  }
  __syncthreads();
#pragma unroll
  for (int j = 0; j < BATCH / 1024; j++) {
    if (bv[j] >= 0) {
      int pos = atomicAdd(&lcur[bv[j]], 1);
      sorted[pos] = ent[j];
      int gp = sbase[bv[j]] + (pos - sofs[bv[j]]);
      gaddr[pos] = (gp < CAP) ? bv[j] * CAP + gp : -1;
    }
  }
  __syncthreads();
  for (int i = t; i < m; i += 1024) {
    int ga = gaddr[i];
    if (ga >= 0) buckets[ga] = sorted[i];
  }
}

// cnt-lite + prep fused: blocks 0..NB-1 do the per-bucket histogram -> dinv
// (4-wave sub-histograms, no same-address contention); block NB converts W
// into MFMA-fragment-ordered bf16 hi/lo (removes prep_k launch).
__global__ __launch_bounds__(256) void cnt_k(const int* __restrict__ buckets,
                                             const int* __restrict__ bcur,
                                             float* __restrict__ dinv,
                                             const float* __restrict__ W,
                                             unsigned short* __restrict__ wh,
                                             unsigned short* __restrict__ wl) {
  int b = blockIdx.x, t = threadIdx.x;
  if (b == NB) {   // ---- prep: W -> wh/wl fragment-ordered bf16 hi/lo
#pragma unroll 4
    for (int i = 0; i < 64; i++) {
      int idx = i * 256 + t;
      int j = idx & 7;
      int lane = (idx >> 3) & 63;
      int pair = idx >> 9;           // kk*4 + nf
      int nf = pair & 3, kk = pair >> 2;
      int k = kk * 32 + (lane >> 4) * 8 + j;
      int n = nf * 16 + (lane & 15);
      float w = W[k * 64 + n];
      unsigned short hh = f2b(w);
      float fh = __uint_as_float((unsigned)hh << 16);
      wh[idx] = hh;
      wl[idx] = f2b(w - fh);
    }
    return;
  }
  __shared__ int c4[4][NPB];
  int w = t >> 6;
  if (t < 128) { c4[0][t & 63] = 0; c4[1][t & 63] = 0; }
  else         { c4[2][t & 63] = 0; c4[3][t & 63] = 0; }
  __syncthreads();
  int m = bcur[b]; if (m > CAP) m = CAP;
  const int* bp = buckets + (size_t)b * CAP;
  for (int i = t; i < m; i += 256) atomicAdd(&c4[w][(bp[i] >> 17) & 63], 1);
  __syncthreads();
  int node = b * NPB + t;
  if (t < NPB && node < NN) {
    int s = c4[0][t] + c4[1][t] + c4[2][t] + c4[3][t];
    dinv[node] = rsqrtf((float)s + 1.0f);
  }
}

// h' = (x @ W_gcn) * dinv[row], bf16 out (dinv baked in so agg needs no
// per-edge dinv loads).
// v13 (MFMA, full-row x preload): per lane the entire 64-float x window is
// issued as 16 upfront global_load_dwordx4; W frags register double-buffered
// one step ahead; sched_barrier(0) fences between steps cap the live set.
// acc += xh*Wh + xh*Wl + xl*Wh (f32 acc; error ~2^-17, numerically == f32).
// C/D layout (m89-verified): col=lane&15, row=(l>>4)*4+reg.
__global__ __launch_bounds__(256) void gemm_k(const float* __restrict__ x,
                                              const unsigned short* __restrict__ wh,
                                              const unsigned short* __restrict__ wl,
                                              const float* __restrict__ dinv,
                                              bf16* __restrict__ h) {
  int t = threadIdx.x;
  int wv = t >> 6, l = t & 63;
  int rowbase = blockIdx.x * 64 + wv * 16;
  int arow = rowbase + (l & 15);
  if (arow >= NN) arow = NN - 1;           // clamp loads, mask stores
  const float* xrow = x + (size_t)arow * 256 + (l >> 4) * 8;

  const bf16x8* whf = (const bf16x8*)wh;   // [ (kk*4+nf)*64 + lane ]
  const bf16x8* wlf = (const bf16x8*)wl;

  f32x4 acc0 = {0.f, 0.f, 0.f, 0.f};
  f32x4 acc1 = acc0, acc2 = acc0, acc3 = acc0;

  // -------- preload the lane's whole x window (16 dwordx4, all in flight)
  float4 x0a = *(const float4*)(xrow +   0), x0b = *(const float4*)(xrow +   4);
  float4 x1a = *(const float4*)(xrow +  32), x1b = *(const float4*)(xrow +  36);
  float4 x2a = *(const float4*)(xrow +  64), x2b = *(const float4*)(xrow +  68);
  float4 x3a = *(const float4*)(xrow +  96), x3b = *(const float4*)(xrow + 100);
  float4 x4a = *(const float4*)(xrow + 128), x4b = *(const float4*)(xrow + 132);
  float4 x5a = *(const float4*)(xrow + 160), x5b = *(const float4*)(xrow + 164);
  float4 x6a = *(const float4*)(xrow + 192), x6b = *(const float4*)(xrow + 196);
  float4 x7a = *(const float4*)(xrow + 224), x7b = *(const float4*)(xrow + 228);

  bf16x8 ha0, ha1, ha2, ha3, la0, la1, la2, la3;   // W set A
  bf16x8 hb0, hb1, hb2, hb3, lb0, lb1, lb2, lb3;   // W set B

#define LOADW(H0, H1, H2, H3, L0, L1, L2, L3, kk)                      \
  {                                                                    \
    int fb_ = (kk) * 256 + l;                                          \
    H0 = whf[fb_]; H1 = whf[fb_ + 64]; H2 = whf[fb_ + 128]; H3 = whf[fb_ + 192]; \
    L0 = wlf[fb_]; L1 = wlf[fb_ + 64]; L2 = wlf[fb_ + 128]; L3 = wlf[fb_ + 192]; \
  }
#define COMPUTE(Xa, Xb, H0, H1, H2, H3, L0, L1, L2, L3)                \
  {                                                                    \
    bf16x8 ah, al;                                                     \
    {                                                                  \
      unsigned short hh_; float fh_;                                   \
      hh_ = f2b(Xa.x); fh_ = __uint_as_float((unsigned)hh_ << 16); ah[0] = (short)hh_; al[0] = (short)f2b(Xa.x - fh_); \
      hh_ = f2b(Xa.y); fh_ = __uint_as_float((unsigned)hh_ << 16); ah[1] = (short)hh_; al[1] = (short)f2b(Xa.y - fh_); \
      hh_ = f2b(Xa.z); fh_ = __uint_as_float((unsigned)hh_ << 16); ah[2] = (short)hh_; al[2] = (short)f2b(Xa.z - fh_); \
      hh_ = f2b(Xa.w); fh_ = __uint_as_float((unsigned)hh_ << 16); ah[3] = (short)hh_; al[3] = (short)f2b(Xa.w - fh_); \
      hh_ = f2b(Xb.x); fh_ = __uint_as_float((unsigned)hh_ << 16); ah[4] = (short)hh_; al[4] = (short)f2b(Xb.x - fh_); \
      hh_ = f2b(Xb.y); fh_ = __uint_as_float((unsigned)hh_ << 16); ah[5] = (short)hh_; al[5] = (short)f2b(Xb.y - fh_); \
      hh_ = f2b(Xb.z); fh_ = __uint_as_float((unsigned)hh_ << 16); ah[6] = (short)hh_; al[6] = (short)f2b(Xb.z - fh_); \
      hh_ = f2b(Xb.w); fh_ = __uint_as_float((unsigned)hh_ << 16); ah[7] = (short)hh_; al[7] = (short)f2b(Xb.w - fh_); \
    }                                                                  \
    acc0 = __builtin_amdgcn_mfma_f32_16x16x32_bf16(ah, H0, acc0, 0, 0, 0); \
    acc1 = __builtin_amdgcn_mfma_f32_16x16x32_bf16(ah, H1, acc1, 0, 0, 0); \
    acc2 = __builtin_amdgcn_mfma_f32_16x16x32_bf16(ah, H2, acc2, 0, 0, 0); \
    acc3 = __builtin_amdgcn_mfma_f32_16x16x32_bf16(ah, H3, acc3, 0, 0, 0); \
    acc0 = __builtin_amdgcn_mfma_f32_16x16x32_bf16(ah, L0, acc0, 0, 0, 0); \
    acc1 = __builtin_amdgcn_mfma_f32_16x16x32_bf16(ah, L1, acc1, 0, 0, 0); \
    acc2 = __builtin_amdgcn_mfma_f32_16x16x32_bf16(ah, L2, acc2, 0, 0, 0); \
    acc3 = __builtin_amdgcn_mfma_f32_16x16x32_bf16(ah, L3, acc3, 0, 0, 0); \
    acc0 = __builtin_amdgcn_mfma_f32_16x16x32_bf16(al, H0, acc0, 0, 0, 0); \
    acc1 = __builtin_amdgcn_mfma_f32_16x16x32_bf16(al, H1, acc1, 0, 0, 0); \
    acc2 = __builtin_amdgcn_mfma_f32_16x16x32_bf16(al, H2, acc2, 0, 0, 0); \
    acc3 = __builtin_amdgcn_mfma_f32_16x16x32_bf16(al, H3, acc3, 0, 0, 0); \
  }
#define SBAR __builtin_amdgcn_sched_barrier(0);

  LOADW(ha0, ha1, ha2, ha3, la0, la1, la2, la3, 0)
  LOADW(hb0, hb1, hb2, hb3, lb0, lb1, lb2, lb3, 1)
  COMPUTE(x0a, x0b, ha0, ha1, ha2, ha3, la0, la1, la2, la3) SBAR
  LOADW(ha0, ha1, ha2, ha3, la0, la1, la2, la3, 2)
  COMPUTE(x1a, x1b, hb0, hb1, hb2, hb3, lb0, lb1, lb2, lb3) SBAR
  LOADW(hb0, hb1, hb2, hb3, lb0, lb1, lb2, lb3, 3)
  COMPUTE(x2a, x2b, ha0, ha1, ha2, ha3, la0, la1, la2, la3) SBAR
  LOADW(ha0, ha1, ha2, ha3, la0, la1, la2, la3, 4)
  COMPUTE(x3a, x3b, hb0, hb1, hb2, hb3, lb0, lb1, lb2, lb3) SBAR
  LOADW(hb0, hb1, hb2, hb3, lb0, lb1, lb2, lb3, 5)
  COMPUTE(x4a, x4b, ha0, ha1, ha2, ha3, la0, la1, la2, la3) SBAR
  LOADW(ha0, ha1, ha2, ha3, la0, la1, la2, la3, 6)
  COMPUTE(x5a, x5b, hb0, hb1, hb2, hb3, lb0, lb1, lb2, lb3) SBAR
  LOADW(hb0, hb1, hb2, hb3, lb0, lb1, lb2, lb3, 7)
  COMPUTE(x6a, x6b, ha0, ha1, ha2, ha3, la0, la1, la2, la3) SBAR
  COMPUTE(x7a, x7b, hb0, hb1, hb2, hb3, lb0, lb1, lb2, lb3)
#undef LOADW
#undef COMPUTE
#undef SBAR

  // epilogue: lane stores rows (l>>4)*4+reg, cols nf*16 + (l&15), * dinv
#pragma unroll
  for (int reg = 0; reg < 4; reg++) {
    int row = rowbase + (l >> 4) * 4 + reg;
    if (row < NN) {
      float dn = dinv[row];
      unsigned short* hp = (unsigned short*)h + (size_t)row * 64 + (l & 15);
      hp[0]  = f2b(acc0[reg] * dn);
      hp[16] = f2b(acc1[reg] * dn);
      hp[32] = f2b(acc2[reg] * dn);
      hp[48] = f2b(acc3[reg] * dn);
    }
  }
}

// Aggregate v7 (fused sort + gather, per-wave histograms/cursors): the
// histogram and scatter passes use per-wave sub-bins (cnt8/wcur[8][64]) so
// same-address LDS atomic contention drops ~8x. LDS ~25KB -> full occupancy
// (round 13 proved agg is occupancy-sensitive -> no MLP fusion).
__global__ __launch_bounds__(512) void agg_k(const bf16* __restrict__ h,
                                             const int* __restrict__ buckets,
                                             const int* __restrict__ bcur,
                                             const float* __restrict__ dinv,
                                             const float* __restrict__ bg,
                                             bf16* __restrict__ hg) {
  __shared__ int ents[CAP];
  __shared__ int srt[CAP];
  __shared__ int cnt8[8][NPB];
  __shared__ int wcur[8][NPB];
  __shared__ int cnt[NPB];
  __shared__ int off[NPB];
  int b = blockIdx.x, t = threadIdx.x;
  int w = t >> 6;
  int m = bcur[b]; if (m > CAP) m = CAP;
  const int* bp = buckets + (size_t)b * CAP;
  for (int i = t; i < 8 * NPB; i += 512) ((int*)cnt8)[i] = 0;
  __syncthreads();
  for (int i = t; i < m; i += 512) {
    int e = bp[i];
    ents[i] = e;
    atomicAdd(&cnt8[w][(e >> 17) & 63], 1);
  }
  __syncthreads();
  if (t < NPB) {
    int s = 0;
#pragma unroll
    for (int ww = 0; ww < 8; ww++) { int c = cnt8[ww][t]; wcur[ww][t] = s; s += c; }
    cnt[t] = s;
  }
  __syncthreads();
  if (t == 0) {
    int s = 0;
#pragma unroll
    for (int i = 0; i < NPB; i++) { off[i] = s; s += cnt[i]; }
  }
  __syncthreads();
  if (t < NPB) {
#pragma unroll
    for (int ww = 0; ww < 8; ww++) wcur[ww][t] += off[t];
  }
  __syncthreads();
  for (int i = t; i < m; i += 512) {
    int e = ents[i];
    int pos = atomicAdd(&wcur[w][(e >> 17) & 63], 1);
    srt[pos] = e & 0x1FFFF;
  }
  __syncthreads();

  int g = t >> 3, fl = t & 7;
  int node = b * NPB + g;
  if (node >= NN) return;
  int start = off[g];
  int deg = cnt[g];
  float dn = dinv[node];
  const unsigned short* hu = (const unsigned short*)h;

  float a0 = 0.f, a1 = 0.f, a2 = 0.f, a3 = 0.f,
        a4 = 0.f, a5 = 0.f, a6 = 0.f, a7 = 0.f;

#define ACCV(V)                                                          \
  {                                                                      \
    a0 += __uint_as_float(V.x << 16); a1 += __uint_as_float(V.x & 0xFFFF0000u); \
    a2 += __uint_as_float(V.y << 16); a3 += __uint_as_float(V.y & 0xFFFF0000u); \
    a4 += __uint_as_float(V.z << 16); a5 += __uint_as_float(V.z & 0xFFFF0000u); \
    a6 += __uint_as_float(V.w << 16); a7 += __uint_as_float(V.w & 0xFFFF0000u); \
  }

  int i = 0;
  for (; i + 4 <= deg; i += 4) {
    int s0 = srt[start + i], s1 = srt[start + i + 1];
    int s2 = srt[start + i + 2], s3 = srt[start + i + 3];
    uint4 v0 = *(const uint4*)(hu + (size_t)s0 * 64 + fl * 8);
    uint4 v1 = *(const uint4*)(hu + (size_t)s1 * 64 + fl * 8);
    uint4 v2 = *(const uint4*)(hu + (size_t)s2 * 64 + fl * 8);
    uint4 v3 = *(const uint4*)(hu + (size_t)s3 * 64 + fl * 8);
    ACCV(v0) ACCV(v1) ACCV(v2) ACCV(v3)
  }
  for (; i < deg; i++) {
    int s0 = srt[start + i];
    uint4 v0 = *(const uint4*)(hu + (size_t)s0 * 64 + fl * 8);
    ACCV(v0)
  }
#undef ACCV

  // epilogue: out = relu( (sum + self) * dn + bias ), bf16 store
  uint4 sv = *(const uint4*)(hu + (size_t)node * 64 + fl * 8);
  const float* bb = bg + fl * 8;
  a0 += __uint_as_float(sv.x << 16); a1 += __uint_as_float(sv.x & 0xFFFF0000u);
  a2 += __uint_as_float(sv.y << 16); a3 += __uint_as_float(sv.y & 0xFFFF0000u);
  a4 += __uint_as_float(sv.z << 16); a5 += __uint_as_float(sv.z & 0xFFFF0000u);
  a6 += __uint_as_float(sv.w << 16); a7 += __uint_as_float(sv.w & 0xFFFF0000u);
  uint4 o;
  o.x = pack2(fmaxf(fmaf(a0, dn, bb[0]), 0.f), fmaxf(fmaf(a1, dn, bb[1]), 0.f));
  o.y = pack2(fmaxf(fmaf(a2, dn, bb[2]), 0.f), fmaxf(fmaf(a3, dn, bb[3]), 0.f));
  o.z = pack2(fmaxf(fmaf(a4, dn, bb[4]), 0.f), fmaxf(fmaf(a5, dn, bb[5]), 0.f));
  o.w = pack2(fmaxf(fmaf(a6, dn, bb[6]), 0.f), fmaxf(fmaf(a7, dn, bb[7]), 0.f));
  *(uint4*)((unsigned short*)hg + (size_t)node * 64 + fl * 8) = o;
}

// Per-thread node MLP: 64 -> 32 -> 16 -> 4 + log_softmax.
__global__ __launch_bounds__(256) void mlp_k(const bf16* __restrict__ hg,
                                             const float* __restrict__ W1, const float* __restrict__ b1,
                                             const float* __restrict__ W2, const float* __restrict__ b2,
                                             const float* __restrict__ W3, const float* __restrict__ b3,
                                             float* __restrict__ out) {
  __shared__ float4 sW1[512];
  __shared__ float4 sW2[128];
  __shared__ float4 sW3[16];
  __shared__ float sb1[32], sb2[16], sb3[4];
  int t = threadIdx.x;
  for (int i = t; i < 512; i += 256) sW1[i] = ((const float4*)W1)[i];
  if (t < 128) sW2[t] = ((const float4*)W2)[t];
  if (t < 16)  sW3[t] = ((const float4*)W3)[t];
  if (t < 32)  sb1[t] = b1[t];
  if (t < 16)  sb2[t] = b2[t];
  if (t < 4)   sb3[t] = b3[t];
  __syncthreads();
  int n = blockIdx.x * 256 + t;
  if (n >= NN) return;
  float xr[64];
  const uint4* hp = (const uint4*)(hg + (size_t)n * 64);
#pragma unroll
  for (int i = 0; i < 8; i++) {
    uint4 v = hp[i];
    unsigned uu[4] = {v.x, v.y, v.z, v.w};
#pragma unroll
    for (int j = 0; j < 4; j++) {
      xr[8 * i + 2 * j]     = __uint_as_float(uu[j] << 16);
      xr[8 * i + 2 * j + 1] = __uint_as_float(uu[j] & 0xFFFF0000u);
    }
  }
  float4 a1[8];
#pragma unroll
  for (int j = 0; j < 8; j++) a1[j] = make_float4(sb1[4 * j], sb1[4 * j + 1], sb1[4 * j + 2], sb1[4 * j + 3]);
#pragma unroll
  for (int f = 0; f < 64; f++) {
    float xv = xr[f];
#pragma unroll
    for (int j = 0; j < 8; j++) fma4(a1[j], xv, sW1[f * 8 + j]);
  }
  float r2[32];
#pragma unroll
  for (int j = 0; j < 8; j++) {
    r2[4 * j + 0] = fmaxf(a1[j].x, 0.f);
    r2[4 * j + 1] = fmaxf(a1[j].y, 0.f);
    r2[4 * j + 2] = fmaxf(a1[j].z, 0.f);
    r2[4 * j + 3] = fmaxf(a1[j].w, 0.f);
  }
  float4 a2[4];
#pragma unroll
  for (int j = 0; j < 4; j++) a2[j] = make_float4(sb2[4 * j], sb2[4 * j + 1], sb2[4 * j + 2], sb2[4 * j + 3]);
#pragma unroll
  for (int f = 0; f < 32; f++) {
    float xv = r2[f];
#pragma unroll
    for (int j = 0; j < 4; j++) fma4(a2[j], xv, sW2[f * 4 + j]);
  }
  float r3[16];
#pragma unroll
  for (int j = 0; j < 4; j++) {
    r3[4 * j + 0] = fmaxf(a2[j].x, 0.f);
    r3[4 * j + 1] = fmaxf(a2[j].y, 0.f);
    r3[4 * j + 2] = fmaxf(a2[j].z, 0.f);
    r3[4 * j + 3] = fmaxf(a2[j].w, 0.f);
  }
  float4 a3 = make_float4(sb3[0], sb3[1], sb3[2], sb3[3]);
#pragma unroll
  for (int f = 0; f < 16; f++) fma4(a3, r3[f], sW3[f]);
  float m = fmaxf(fmaxf(a3.x, a3.y), fmaxf(a3.z, a3.w));
  float s = expf(a3.x - m) + expf(a3.y - m) + expf(a3.z - m) + expf(a3.w - m);
  float l = m + logf(s);
  ((float4*)out)[n] = make_float4(a3.x - l, a3.y - l, a3.z - l, a3.w - l);
}

extern "C" void kernel_launch(void* const* d_in, const int* in_sizes, int n_in,
                              void* d_out, int out_size, void* d_ws, size_t ws_size,
                              hipStream_t stream) {
  const float* x  = (const float*)d_in[0];
  const void* eidx = d_in[1];
  const float* Wg = (const float*)d_in[2];
  const float* bg = (const float*)d_in[3];
  const float* W1 = (const float*)d_in[4];
  const float* b1 = (const float*)d_in[5];
  const float* W2 = (const float*)d_in[6];
  const float* b2 = (const float*)d_in[7];
  const float* W3 = (const float*)d_in[8];
  const float* b3 = (const float*)d_in[9];

  char* ws = (char*)d_ws;
  bf16*  h       = (bf16*) (ws + 0);           // 12,800,000 B
  bf16*  hg      = (bf16*) (ws + 12800000);    // 12,800,000 B
  int*   buckets = (int*)  (ws + 25600000);    // 1564*2560*4 = 16,015,360 B
  float* dinv    = (float*)(ws + 41615360);    //    400,000 B
  int*   bcur    = (int*)  (ws + 42415360);    //      6,256 B
  // wh/wl (32KB each) live in the hg region: hg is only WRITTEN by agg_k,
  // which runs after gemm_k has finished reading wh/wl (stream-ordered).
  unsigned short* wh = (unsigned short*)(ws + 12800000);
  unsigned short* wl = (unsigned short*)(ws + 12800000 + 32768);

  hipMemsetAsync(bcur, 0, NB * sizeof(int), stream);
  bin_k<<<(NE + BATCH - 1) / BATCH, 1024, 0, stream>>>(eidx, bcur, buckets);
  cnt_k<<<NB + 1, 256, 0, stream>>>(buckets, bcur, dinv, Wg, wh, wl);
  gemm_k<<<NGB, 256, 0, stream>>>(x, wh, wl, dinv, h);
  agg_k<<<NB, 512, 0, stream>>>(h, buckets, bcur, dinv, bg, hg);
  mlp_k<<<(NN + 255) / 256, 256, 0, stream>>>(hg, W1, b1, W2, b2, W3, b3, (float*)d_out);
}